// Round 4
// baseline (715.991 us; speedup 1.0000x reference)
//
#include <hip/hip_runtime.h>
#include <hip/hip_bf16.h>

#define L_LAYERS 4
#define B_DIM 256
#define H_DIM 65536
#define KC 1024                    // K-chunk per block -> 64 splits per layer
#define BK 32                      // K per MFMA step
#define NKT (KC / BK)              // 32 K-steps
#define NKZ (H_DIM / KC)           // 64
#define NSLICE (L_LAYERS * NKZ)    // 256 partial-Gram slices
#define LDSTR 40                   // shorts per LDS row (80 B: conflict-free for b128 frag reads)

using bf16x8_t = __attribute__((ext_vector_type(8))) short;            // MFMA A/B operand
using shortx8  = __attribute__((ext_vector_type(8))) short;            // 16-byte LDS store
using ushortx4 = __attribute__((ext_vector_type(4))) unsigned short;   // 8-byte global store
using floatx4  = __attribute__((ext_vector_type(4))) float;            // MFMA accumulator

__device__ __forceinline__ unsigned short f2bf(float f) {
    unsigned u = __float_as_uint(f);
    return (unsigned short)((u + 0x7fffu + ((u >> 16) & 1u)) >> 16);
}
__device__ __forceinline__ float bf2f(unsigned short h) {
    return __uint_as_float((unsigned)h << 16);
}

// One block per (layer, kz): reads 256 rows x KC floats EXACTLY ONCE,
// computes the full 256x256 Gram partial, stores bf16 slice + fp32 diag.
__global__ __launch_bounds__(512, 2) void gram_kernel(const float* __restrict__ hs,
                                                      unsigned short* __restrict__ S,
                                                      float* __restrict__ Dg) {
    __shared__ short lds[2][B_DIM * LDSTR];   // 2 x 20 KB (double buffer)

    const int tid = threadIdx.x;
    const int bx  = blockIdx.x;            // 0..255
    const int l   = bx >> 6;
    const int kz  = bx & (NKZ - 1);

    const int wave = tid >> 6, lane = tid & 63;
    const int wm = wave >> 1;              // 0..3: 64-row strip
    const int wn = wave & 1;               // 0..1: 128-col strip
    const int mrow = lane & 15, quad = lane >> 4;

    // staging: thread t covers row r = t>>1, floats [h*16, h*16+16)
    const int r = tid >> 1;
    const int h = tid & 1;
    const float* gp = hs + ((size_t)l * B_DIM + r) * H_DIM + (size_t)kz * KC + h * 16;
    const int ldsw = r * LDSTR + h * 16;   // short units

    floatx4 acc[4][8];
#pragma unroll
    for (int i = 0; i < 4; ++i)
#pragma unroll
        for (int j = 0; j < 8; ++j) acc[i][j] = (floatx4)0.0f;

    float4 pv0, pv1, pv2, pv3;
#define LOADPV(off) do { const float* _g = gp + (off); \
        pv0 = *(const float4*)(_g + 0);  pv1 = *(const float4*)(_g + 4); \
        pv2 = *(const float4*)(_g + 8);  pv3 = *(const float4*)(_g + 12); } while (0)
#define STAGE(buf) do { shortx8 w0, w1; \
        w0[0] = (short)f2bf(pv0.x); w0[1] = (short)f2bf(pv0.y); \
        w0[2] = (short)f2bf(pv0.z); w0[3] = (short)f2bf(pv0.w); \
        w0[4] = (short)f2bf(pv1.x); w0[5] = (short)f2bf(pv1.y); \
        w0[6] = (short)f2bf(pv1.z); w0[7] = (short)f2bf(pv1.w); \
        w1[0] = (short)f2bf(pv2.x); w1[1] = (short)f2bf(pv2.y); \
        w1[2] = (short)f2bf(pv2.z); w1[3] = (short)f2bf(pv2.w); \
        w1[4] = (short)f2bf(pv3.x); w1[5] = (short)f2bf(pv3.y); \
        w1[6] = (short)f2bf(pv3.z); w1[7] = (short)f2bf(pv3.w); \
        *(shortx8*)&lds[buf][ldsw]     = w0; \
        *(shortx8*)&lds[buf][ldsw + 8] = w1; } while (0)

    LOADPV(0);
    STAGE(0);            // slice 0 -> buf 0
    LOADPV(BK);          // prefetch slice 1
    __syncthreads();

    for (int kt = 0; kt < NKT; ++kt) {
        const int cur = kt & 1;
        if (kt + 1 < NKT) {
            STAGE(cur ^ 1);                      // slice kt+1 into other buffer
            if (kt + 2 < NKT) LOADPV((kt + 2) * BK);
        }
        bf16x8_t af[4], bfv[8];
#pragma unroll
        for (int i = 0; i < 4; ++i)
            af[i] = *(const bf16x8_t*)&lds[cur][(wm * 64 + i * 16 + mrow) * LDSTR + quad * 8];
#pragma unroll
        for (int j = 0; j < 8; ++j)
            bfv[j] = *(const bf16x8_t*)&lds[cur][(wn * 128 + j * 16 + mrow) * LDSTR + quad * 8];
#pragma unroll
        for (int i = 0; i < 4; ++i)
#pragma unroll
            for (int j = 0; j < 8; ++j)
                acc[i][j] = __builtin_amdgcn_mfma_f32_16x16x32_bf16(af[i], bfv[j], acc[i][j], 0, 0, 0);
        __syncthreads();
    }
#undef LOADPV
#undef STAGE

    // Epilogue. Gram partial is SYMMETRIC, so storing [col][row] == [row][col].
    // Lane holds 4 consecutive ROWS per (i,j) -> contiguous ushort4 store at [col][rowb].
    unsigned short* Ssl = S + (size_t)bx * (B_DIM * B_DIM);
#pragma unroll
    for (int i = 0; i < 4; ++i) {
        const int rowb = wm * 64 + i * 16 + quad * 4;
#pragma unroll
        for (int j = 0; j < 8; ++j) {
            const int col = wn * 128 + j * 16 + mrow;
            ushortx4 v;
            v[0] = f2bf(acc[i][j][0]); v[1] = f2bf(acc[i][j][1]);
            v[2] = f2bf(acc[i][j][2]); v[3] = f2bf(acc[i][j][3]);
            *(ushortx4*)&Ssl[col * B_DIM + rowb] = v;
        }
    }
    // fp32 diagonal -> compact Dg[slice][row]
#pragma unroll
    for (int i = 0; i < 4; ++i)
#pragma unroll
        for (int rr = 0; rr < 4; ++rr) {
            const int row = wm * 64 + i * 16 + quad * 4 + rr;
            const int cr  = row - wn * 128;
            if (cr >= 0 && cr < 128 && (cr & 15) == mrow)
                Dg[bx * B_DIM + row] = acc[i][cr >> 4][rr];
        }
}

// rnorm[l][j] = rsqrt( sum_kz Dg[l*NKZ+kz][j] )
__global__ __launch_bounds__(256) void norm_kernel(const float* __restrict__ Dg,
                                                   float* __restrict__ rnorm) {
    const int l = blockIdx.x, j = threadIdx.x;
    float s = 0.0f;
#pragma unroll
    for (int kz = 0; kz < NKZ; ++kz)
        s += Dg[((l * NKZ + kz) << 8) + j];
    rnorm[(l << 8) + j] = rsqrtf(s);
}

// Fused kz-reduce + loss: block (i,l), thread j sums bf16 slices then does softmax-ratio.
__global__ __launch_bounds__(256) void loss_kernel(const unsigned short* __restrict__ S,
                                                   const float* __restrict__ rnorm,
                                                   const int* __restrict__ task,
                                                   float* __restrict__ out) {
    const int i = blockIdx.x, l = blockIdx.y, j = threadIdx.x;

    // block-uniform int64-vs-int32 detection for task_type (proven in R2)
    __shared__ int s_odd_nz;
    if (j == 0) s_odd_nz = 0;
    __syncthreads();
    if (j < 128 && task[2 * j + 1] != 0) s_odd_nz = 1;
    __syncthreads();
    const bool is64 = (s_odd_nz == 0);

    const unsigned short* base = S + ((size_t)l * NKZ) * (B_DIM * B_DIM) + i * B_DIM + j;
    float g = 0.0f;
#pragma unroll
    for (int kz = 0; kz < NKZ; ++kz)
        g += bf2f(base[(size_t)kz * (B_DIM * B_DIM)]);

    const float nd = g * rnorm[(l << 8) + i] * rnorm[(l << 8) + j];
    const float d2 = fmaxf(2.0f - 2.0f * nd, 0.0f);
    const float w  = __expf(-2.0f * d2);   // exp(-d2 / 0.5)

    const int ti = is64 ? task[2 * i] : task[i];
    const int tj = is64 ? task[2 * j] : task[j];
    const float pm = (ti == tj && i != j) ? 1.0f : 0.0f;

    float a = w * pm, b = w;
#pragma unroll
    for (int off = 32; off > 0; off >>= 1) {
        a += __shfl_down(a, off);
        b += __shfl_down(b, off);
    }
    __shared__ float sa[4], sb[4];
    const int wv = j >> 6, ln = j & 63;
    if (ln == 0) { sa[wv] = a; sb[wv] = b; }
    __syncthreads();
    if (j == 0) {
        const float A  = sa[0] + sa[1] + sa[2] + sa[3];
        const float Bb = sb[0] + sb[1] + sb[2] + sb[3];
        const float c  = -logf((A + 1e-8f) / (Bb + 1e-8f)) * (0.2f / 1024.0f);
        atomicAdd(out, c);
    }
}

extern "C" void kernel_launch(void* const* d_in, const int* in_sizes, int n_in,
                              void* d_out, int out_size, void* d_ws, size_t ws_size,
                              hipStream_t stream) {
    const float* hs   = (const float*)d_in[0];
    const int*   task = (const int*)d_in[1];
    float*       out  = (float*)d_out;

    unsigned short* S  = (unsigned short*)d_ws;                     // 33.5 MB bf16 slices
    float* Dg    = (float*)(S + (size_t)NSLICE * B_DIM * B_DIM);    // 256 KB diag partials
    float* rnorm = Dg + (size_t)NSLICE * B_DIM;                     // 4 KB

    hipMemsetAsync(out, 0, sizeof(float), stream);

    gram_kernel<<<dim3(NSLICE), dim3(512), 0, stream>>>(hs, S, Dg);
    norm_kernel<<<dim3(L_LAYERS), dim3(256), 0, stream>>>(Dg, rnorm);
    loss_kernel<<<dim3(B_DIM, L_LAYERS), dim3(256), 0, stream>>>(S, rnorm, task, out);
}

// Round 5
// 429.386 us; speedup vs baseline: 1.6675x; 1.6675x over previous
//
#include <hip/hip_runtime.h>
#include <hip/hip_bf16.h>

#define L_LAYERS 4
#define B_DIM 256
#define H_DIM 65536
#define KC 1024                    // K-chunk per block -> 64 splits per layer
#define BK 32                      // K per MFMA step
#define NKT (KC / BK)              // 32 K-steps
#define NKZ (H_DIM / KC)           // 64
#define NSLICE (L_LAYERS * NKZ)    // 256 partial-Gram slices
#define LDSTR 40                   // shorts per LDS row (80 B: <=2-way bank conflict, free)

using bf16x8_t = __attribute__((ext_vector_type(8))) short;   // MFMA A/B operand
using shortx8  = __attribute__((ext_vector_type(8))) short;   // 16-byte LDS store
using floatx4  = __attribute__((ext_vector_type(4))) float;   // MFMA accumulator

__device__ __forceinline__ unsigned short f2bf(float f) {
    unsigned u = __float_as_uint(f);
    return (unsigned short)((u + 0x7fffu + ((u >> 16) & 1u)) >> 16);
}

// One block per (layer, kz): 1024 threads, 16 waves in 4x4 grid of 64x64 tiles.
// Reads 256 rows x KC floats exactly once; acc = 64 VGPR/lane -> no spills.
__global__ __launch_bounds__(1024, 4) void gram_kernel(const float* __restrict__ hs,
                                                       float* __restrict__ S,
                                                       float* __restrict__ Dg) {
    __shared__ short lds[B_DIM * LDSTR];   // 256 x 40 shorts = 20 KB

    const int tid = threadIdx.x;
    const int bx  = blockIdx.x;            // 0..255
    const int l   = bx >> 6;
    const int kz  = bx & (NKZ - 1);

    const int wave = tid >> 6, lane = tid & 63;
    const int wm = wave >> 2;              // 0..3: 64-row strip
    const int wn = wave & 3;               // 0..3: 64-col strip
    const int mrow = lane & 15, quad = lane >> 4;

    // staging: thread t covers row = t>>2, floats [seg*8, seg*8+8)
    const int row = tid >> 2;
    const int seg = tid & 3;
    const float* gp = hs + ((size_t)l * B_DIM + row) * H_DIM + (size_t)kz * KC + seg * 8;
    const int ldsw = row * LDSTR + seg * 8;   // short units

    floatx4 acc[4][4];
#pragma unroll
    for (int i = 0; i < 4; ++i)
#pragma unroll
        for (int j = 0; j < 4; ++j) acc[i][j] = (floatx4)0.0f;

    float4 pv0, pv1;
#define LOADPV(off) do { const float* _g = gp + (off); \
        pv0 = *(const float4*)(_g); pv1 = *(const float4*)(_g + 4); } while (0)

    LOADPV(0);
    for (int kt = 0; kt < NKT; ++kt) {
        shortx8 w;
        w[0] = (short)f2bf(pv0.x); w[1] = (short)f2bf(pv0.y);
        w[2] = (short)f2bf(pv0.z); w[3] = (short)f2bf(pv0.w);
        w[4] = (short)f2bf(pv1.x); w[5] = (short)f2bf(pv1.y);
        w[6] = (short)f2bf(pv1.z); w[7] = (short)f2bf(pv1.w);
        *(shortx8*)&lds[ldsw] = w;         // prev iter's trailing barrier protects this
        if (kt + 1 < NKT) LOADPV((kt + 1) * BK);   // lands during MFMA phase
        __syncthreads();

        bf16x8_t bfv[4];
#pragma unroll
        for (int j = 0; j < 4; ++j)
            bfv[j] = *(const bf16x8_t*)&lds[(wn * 64 + j * 16 + mrow) * LDSTR + quad * 8];
#pragma unroll
        for (int i = 0; i < 4; ++i) {
            const bf16x8_t af = *(const bf16x8_t*)&lds[(wm * 64 + i * 16 + mrow) * LDSTR + quad * 8];
#pragma unroll
            for (int j = 0; j < 4; ++j)
                acc[i][j] = __builtin_amdgcn_mfma_f32_16x16x32_bf16(af, bfv[j], acc[i][j], 0, 0, 0);
        }
        __syncthreads();
    }
#undef LOADPV

    // Coalesced fp32 epilogue: C/D layout col=lane&15, row=quad*4+reg (m89/m91).
    float* Ssl = S + (size_t)bx * (B_DIM * B_DIM);
#pragma unroll
    for (int i = 0; i < 4; ++i)
#pragma unroll
        for (int j = 0; j < 4; ++j)
#pragma unroll
            for (int rr = 0; rr < 4; ++rr) {
                const int r2 = wm * 64 + i * 16 + quad * 4 + rr;
                const int c2 = wn * 64 + j * 16 + mrow;
                Ssl[r2 * B_DIM + c2] = acc[i][j][rr];
            }
    // fp32 diagonal -> compact Dg[slice][row]; diagonal waves (wm==wn) only,
    // lane condition mrow == quad*4+rr picks exactly one lane per row.
    if (wm == wn) {
#pragma unroll
        for (int i = 0; i < 4; ++i)
#pragma unroll
            for (int rr = 0; rr < 4; ++rr) {
                if (mrow == quad * 4 + rr) {
                    const int r2 = wm * 64 + i * 16 + quad * 4 + rr;
                    Dg[bx * B_DIM + r2] = acc[i][i][rr];
                }
            }
    }
}

// rnorm[l][j] = rsqrt( sum_kz Dg[l*NKZ+kz][j] )
__global__ __launch_bounds__(256) void norm_kernel(const float* __restrict__ Dg,
                                                   float* __restrict__ rnorm) {
    const int l = blockIdx.x, j = threadIdx.x;
    float s = 0.0f;
#pragma unroll
    for (int kz = 0; kz < NKZ; ++kz)
        s += Dg[((l * NKZ + kz) << 8) + j];
    rnorm[(l << 8) + j] = rsqrtf(s);
}

// Fused kz-reduce + loss: block (i,l), thread j sums fp32 slices then softmax-ratio.
__global__ __launch_bounds__(256) void loss_kernel(const float* __restrict__ S,
                                                   const float* __restrict__ rnorm,
                                                   const int* __restrict__ task,
                                                   float* __restrict__ out) {
    const int i = blockIdx.x, l = blockIdx.y, j = threadIdx.x;

    // block-uniform int64-vs-int32 detection for task_type (proven in R2)
    __shared__ int s_odd_nz;
    if (j == 0) s_odd_nz = 0;
    __syncthreads();
    if (j < 128 && task[2 * j + 1] != 0) s_odd_nz = 1;
    __syncthreads();
    const bool is64 = (s_odd_nz == 0);

    const float* base = S + ((size_t)l * NKZ) * (B_DIM * B_DIM) + i * B_DIM + j;
    float g = 0.0f;
#pragma unroll
    for (int kz = 0; kz < NKZ; ++kz)
        g += base[(size_t)kz * (B_DIM * B_DIM)];

    const float nd = g * rnorm[(l << 8) + i] * rnorm[(l << 8) + j];
    const float d2 = fmaxf(2.0f - 2.0f * nd, 0.0f);
    const float w  = __expf(-2.0f * d2);   // exp(-d2 / 0.5)

    const int ti = is64 ? task[2 * i] : task[i];
    const int tj = is64 ? task[2 * j] : task[j];
    const float pm = (ti == tj && i != j) ? 1.0f : 0.0f;

    float a = w * pm, b = w;
#pragma unroll
    for (int off = 32; off > 0; off >>= 1) {
        a += __shfl_down(a, off);
        b += __shfl_down(b, off);
    }
    __shared__ float sa[4], sb[4];
    const int wv = j >> 6, ln = j & 63;
    if (ln == 0) { sa[wv] = a; sb[wv] = b; }
    __syncthreads();
    if (j == 0) {
        const float A  = sa[0] + sa[1] + sa[2] + sa[3];
        const float Bb = sb[0] + sb[1] + sb[2] + sb[3];
        const float c  = -logf((A + 1e-8f) / (Bb + 1e-8f)) * (0.2f / 1024.0f);
        atomicAdd(out, c);
    }
}

extern "C" void kernel_launch(void* const* d_in, const int* in_sizes, int n_in,
                              void* d_out, int out_size, void* d_ws, size_t ws_size,
                              hipStream_t stream) {
    const float* hs   = (const float*)d_in[0];
    const int*   task = (const int*)d_in[1];
    float*       out  = (float*)d_out;

    float* S     = (float*)d_ws;                                 // 64 MB fp32 slices
    float* Dg    = S + (size_t)NSLICE * B_DIM * B_DIM;           // 256 KB diag partials
    float* rnorm = Dg + (size_t)NSLICE * B_DIM;                  // 4 KB

    hipMemsetAsync(out, 0, sizeof(float), stream);

    gram_kernel<<<dim3(NSLICE), dim3(1024), 0, stream>>>(hs, S, Dg);
    norm_kernel<<<dim3(L_LAYERS), dim3(256), 0, stream>>>(Dg, rnorm);
    loss_kernel<<<dim3(B_DIM, L_LAYERS), dim3(256), 0, stream>>>(S, rnorm, task, out);
}